// Round 8
// baseline (143.344 us; speedup 1.0000x reference)
//
#include <hip/hip_runtime.h>
#include <hip/hip_bf16.h>

// EfficientAttention: x(4,256,64,64) -> qkv(192ch) -> attn(N=4096,c=64) -> proj(256ch)
// k_prep: qkv weights fp32->bf16 frag layout (0.125 scale folded into Q rows/bias).
// k_qkv : MFMA 32x32x16; Q,K,V written in frag-swizzled layouts:
//   Qf/Kf: [b][chunk32][kk(4)][lane(64)][8]
//   Vf   : [b][chunk32][ct(2)ks(2)][lane(64)][j(8)] = producer reg order
// k_attn: LDS-DMA double-buffered K-loop; S^T = K^T Q; P = poly-exp(S) --
//   NO transcendentals (r0-r7 invariant: time ∝ v_exp count, ~150 cyc/inst;
//   deg-8 Taylor in pure FMA bypasses the trans pipe); S regs ARE the O-MFMA
//   A-operand (V k-slots pre-permuted); LDS-atomic combine; fused proj.

#define N_TOK 4096
#define CDIM  64
#define DIM   256
#define NBAT  4

typedef __attribute__((ext_vector_type(8)))  short          short8;
typedef __attribute__((ext_vector_type(8)))  unsigned short ushort8_t;
typedef __attribute__((ext_vector_type(4)))  unsigned short ushort4_t;
typedef __attribute__((ext_vector_type(4)))  unsigned int   uint4_t;
typedef __attribute__((ext_vector_type(4)))  float          float4_t;
typedef __attribute__((ext_vector_type(16))) float          float16_t;

#define QSC  0.125f   /* softmax scale, folded into Q weights/bias */

// e^t via deg-8 Taylor (Horner, 8 FMA, no trans pipe). |t| <= ~1.5 in practice
// (t = 0.125*q.k, std ~0.1); rel err ~6e-6 at |t|<=1, ~1e-3 at |t|=2.
__device__ __forceinline__ float pexp(float t) {
  float p = fmaf(2.4801587e-5f, t, 1.9841270e-4f);   // 1/8!, 1/7!
  p = fmaf(p, t, 1.3888889e-3f);                     // 1/6!
  p = fmaf(p, t, 8.3333333e-3f);                     // 1/5!
  p = fmaf(p, t, 4.1666667e-2f);                     // 1/4!
  p = fmaf(p, t, 1.6666667e-1f);                     // 1/3!
  p = fmaf(p, t, 0.5f);
  p = fmaf(p, t, 1.0f);
  p = fmaf(p, t, 1.0f);
  return p;
}

__device__ __forceinline__ unsigned short f2bf(float f) {
  unsigned int u = __builtin_bit_cast(unsigned int, f);
  u += 0x7fffu + ((u >> 16) & 1u);            // RNE
  return (unsigned short)(u >> 16);
}

// packed f32x2 -> bf16x2 dword (v_cvt_pk_bf16_f32 on gfx950, RNE)
__device__ __forceinline__ unsigned int pkcv(float a, float b) {
  __hip_bfloat162 h = __float22bfloat162_rn(make_float2(a, b));
  unsigned int r; __builtin_memcpy(&r, &h, 4); return r;
}

__device__ __forceinline__ short8 ld8(const unsigned short* p) {
  return __builtin_bit_cast(short8, *(const ushort8_t*)p);
}

__device__ __forceinline__ short8 pack8f(float4_t a, float4_t b) {
  uint4_t u;
  u[0] = pkcv(a[0], a[1]); u[1] = pkcv(a[2], a[3]);
  u[2] = pkcv(b[0], b[1]); u[3] = pkcv(b[2], b[3]);
  return __builtin_bit_cast(short8, u);
}

__device__ __forceinline__ float16_t z16() {
  float16_t r;
#pragma unroll
  for (int i = 0; i < 16; ++i) r[i] = 0.0f;
  return r;
}

// async global->LDS DMA: 64 lanes x 16B; LDS dst = uniform base + lane*16
typedef __attribute__((address_space(1))) const void* gvp;
typedef __attribute__((address_space(3))) void*       lvp;
__device__ __forceinline__ void dma16(const unsigned short* g, unsigned short* l) {
  __builtin_amdgcn_global_load_lds((gvp)g, (lvp)l, 16, 0, 0);
}

#define MFMA(a, b, c) __builtin_amdgcn_mfma_f32_32x32x16_bf16((a), (b), (c), 0, 0, 0)

// ws layout (u16 units)
#define QOFF  0                // 4*128*4*512 = 1048576 each
#define KOFF  1048576
#define VOFF  2097152
#define WQOFF 3145728          // 192*256
#define BSOFF 3194880          // scaled qkv bias, fp32 (192)

// ---------------------------------------------------------------------------
// k_prep: grid 24 x 256. qkv_w -> bf16 frag layout (Q rows scaled by QSC);
// bias -> fp32 with Q-scale fold.
// ---------------------------------------------------------------------------
__global__ void k_prep(const float* __restrict__ qw, const float* __restrict__ qb,
                       unsigned short* __restrict__ wqs, float* __restrict__ bs)
{
  const int g = blockIdx.x * 256 + threadIdx.x;   // 0..6143
  {
    const int lane = g & 63, grp = g >> 6;
    const int w6 = grp >> 4, kk = grp & 15;
    const int o = w6 * 32 + (lane & 31);
    const int c = kk * 16 + (lane >> 5) * 8;
    const float sc = (o < 64) ? QSC : 1.0f;
    const float* src = qw + o * 256 + c;
    ushort8_t u;
#pragma unroll
    for (int j = 0; j < 8; ++j) u[j] = f2bf(src[j] * sc);
    *(ushort8_t*)(wqs + g * 8) = u;
  }
  if (g < 48) {
    float4_t f = *(const float4_t*)(qb + g * 4);
    float4_t o;
#pragma unroll
    for (int j = 0; j < 4; ++j) o[j] = f[j] * ((g * 4 + j) < 64 ? QSC : 1.0f);
    *(float4_t*)(bs + g * 4) = o;
  }
}

// ---------------------------------------------------------------------------
// k_qkv: grid 512 x 384 thr (6 waves). Block: 32-token tile, all 192 o.
// Waves 0-3 (Q,K): C[o rows][n cols] -> frag stores.
// Waves 4-5 (V):   swapped operands -> C[token rows][c cols], producer order.
// ---------------------------------------------------------------------------
#define RS 132   // Xl row stride in dwords

__global__ __launch_bounds__(384, 3) void k_qkv(
    const float* __restrict__ x, const unsigned short* __restrict__ wqs,
    const float* __restrict__ bs, unsigned short* __restrict__ Qf,
    unsigned short* __restrict__ Kf, unsigned short* __restrict__ Vf)
{
  __shared__ unsigned int Xl[32 * RS];
  const int id = blockIdx.x;
  const int b  = (id >> 1) & 3;
  const int nt = (id & 1) | ((id >> 3) << 1);   // 0..127 (32-token chunk)
  const int t  = threadIdx.x;
  const int n0g = nt * 32;

  if (t < 256) {
    const int n0  = (t & 7) * 4;
    const int cpb = t >> 3;                      // 0..31
#pragma unroll
    for (int p = 0; p < 4; ++p) {
      const int cp = cpb + 32 * p, c = cp * 2;
      const float* xb = x + (((size_t)(b * DIM + c)) << 12) + n0g + n0;
      float4_t a = *(const float4_t*)xb;
      float4_t d = *(const float4_t*)(xb + 4096);
#pragma unroll
      for (int j = 0; j < 4; ++j)
        Xl[(n0 + j) * RS + cp] = pkcv(a[j], d[j]);
    }
  }
  __syncthreads();

  const int w = t >> 6, lane = t & 63, l31 = lane & 31, lh = lane >> 5;
  const unsigned short* wrow = wqs + ((w * 16) << 9) + lane * 8;
  const unsigned int*   xrow = &Xl[l31 * RS + lh * 4];

  float16_t a0 = z16(), a1 = z16();
  if (w < 4) {
#pragma unroll
    for (int kk = 0; kk < 8; ++kk) {
      short8 x0 = __builtin_bit_cast(short8, *(const uint4_t*)(xrow + (2 * kk) * 8));
      short8 x1 = __builtin_bit_cast(short8, *(const uint4_t*)(xrow + (2 * kk + 1) * 8));
      short8 w0 = ld8(wrow + ((2 * kk) << 9));
      short8 w1 = ld8(wrow + ((2 * kk + 1) << 9));
      a0 = MFMA(w0, x0, a0);                     // C[o rows][n cols]
      a1 = MFMA(w1, x1, a1);
    }
  } else {
#pragma unroll
    for (int kk = 0; kk < 8; ++kk) {
      short8 x0 = __builtin_bit_cast(short8, *(const uint4_t*)(xrow + (2 * kk) * 8));
      short8 x1 = __builtin_bit_cast(short8, *(const uint4_t*)(xrow + (2 * kk + 1) * 8));
      short8 w0 = ld8(wrow + ((2 * kk) << 9));
      short8 w1 = ld8(wrow + ((2 * kk + 1) << 9));
      a0 = MFMA(x0, w0, a0);                     // C[token rows][c cols]
      a1 = MFMA(x1, w1, a1);
    }
  }
#pragma unroll
  for (int e = 0; e < 16; ++e) a0[e] += a1[e];

  if (w < 4) {
    unsigned short* dst = (w < 2) ? Qf : Kf;
    const int w2 = w & 1;                        // c64-half of Q or K
#pragma unroll
    for (int p = 0; p < 4; ++p) {
      const int o = w * 32 + p * 8 + lh * 4;     // global qkv channel
      float4_t bv = *(const float4_t*)(bs + o);
      ushort4_t pk4;
#pragma unroll
      for (int q = 0; q < 4; ++q) pk4[q] = f2bf(a0[p * 4 + q] + bv[q]);
      const int kkt = w2 * 2 + (p >> 1);
      *(ushort4_t*)(dst + ((((b * 128 + nt) * 4 + kkt) << 9)
                           + (l31 + 32 * (p & 1)) * 8 + lh * 4)) = pk4;
    }
  } else {
    const int ct = w - 4;                        // c-group of V
    const float bvs = bs[128 + ct * 32 + l31];
#pragma unroll
    for (int ks = 0; ks < 2; ++ks) {
      ushort8_t pk8;
#pragma unroll
      for (int j = 0; j < 8; ++j) pk8[j] = f2bf(a0[ks * 8 + j] + bvs);
      *(ushort8_t*)(Vf + ((((b * 128 + nt) * 4 + ct * 2 + ks) << 9)
                          + lane * 8)) = pk8;
    }
  }
}

// ---------------------------------------------------------------------------
// k_attn: grid 256 x 512 thr (8 waves). Block: 64 q-rows.
// Outer loop: 32 tiles of 128 tokens, LDS double-buffered via global_load_lds.
// Staging role: waves 0-3 -> K chunk wv; waves 4-7 -> V chunk wv-4 (4KB each).
// Compute role: wave wv -> m-chunk (wv>>1), n-subtile (wv&1).
// ---------------------------------------------------------------------------
#define OS   68    // Oacc row stride (fp32)
#define OLS  72    // Ol row stride (bf16)
#define NACC (64 * OS + 64)

__global__ __launch_bounds__(512, 2) void k_attn(
    const unsigned short* __restrict__ Qf, const unsigned short* __restrict__ Kf,
    const unsigned short* __restrict__ Vf, const float* __restrict__ pw,
    const float* __restrict__ pb, float* __restrict__ out)
{
  __shared__ __align__(16) unsigned short KV[2][2][8192];  // [buf][K|V][4chunk*2048]
  __shared__ float Oacc[NACC];                             // O[n][c] + den tail
  __shared__ __align__(16) unsigned short Ol[64 * OLS];

  const int id = blockIdx.x;
  const int b  = (id >> 1) & 3;
  const int nt = (id & 1) | ((id >> 3) << 1);        // 0..63
  const int t  = threadIdx.x;
  const int wv = t >> 6, lane = t & 63, l31 = lane & 31, lh = lane >> 5;
  const int mq = wv >> 1, nsub = wv & 1;

  for (int i = t; i < NACC; i += 512) Oacc[i] = 0.0f;

  // staging source for this wave (chunk stride = 2048 u16 = 4KB)
  const int kvsel = (wv < 4) ? 0 : 1;
  const int sc_   = wv & 3;
  const unsigned short* sg = ((wv < 4) ? Kf : Vf)
                             + (((size_t)(b * 128 + sc_)) << 11) + lane * 8;

  // Q frags (QSC pre-folded)
  short8 qf[4];
#pragma unroll
  for (int kk = 0; kk < 4; ++kk)
    qf[kk] = ld8(Qf + (((b * 128 + nt * 2 + nsub) * 4 + kk) << 9) + lane * 8);

  // stage tile 0 into buf 0
#pragma unroll
  for (int kk = 0; kk < 4; ++kk)
    dma16(sg + (kk << 9), &KV[0][kvsel][(sc_ << 11) + (kk << 9)]);

  float16_t oc0 = z16(), oc1 = z16();
  float den = 0.0f;

  __syncthreads();   // Oacc zeroed + tile 0 resident (vmcnt drained pre-barrier)

  for (int t4 = 0; t4 < 32; ++t4) {
    const int cur = t4 & 1;

    // stage tile t4+1 into the other buffer (in flight across this compute)
    if (t4 < 31) {
      const unsigned short* g = sg + ((size_t)(t4 + 1) << 13);
#pragma unroll
      for (int kk = 0; kk < 4; ++kk)
        dma16(g + (kk << 9), &KV[cur ^ 1][kvsel][(sc_ << 11) + (kk << 9)]);
    }

    // K frags for my m-chunk
    const unsigned short* kl = &KV[cur][0][mq << 11];
    const unsigned short* vl = &KV[cur][1][mq << 11];
    short8 kf0 = ld8(kl + lane * 8);
    short8 kf1 = ld8(kl + 512 + lane * 8);
    short8 kf2 = ld8(kl + 1024 + lane * 8);
    short8 kf3 = ld8(kl + 1536 + lane * 8);

    // S^T tile: lane col n = l31, row m = (e&3)+8*(e>>2)+4*lh
    float16_t s = z16();
    s = MFMA(kf0, qf[0], s);
    s = MFMA(kf1, qf[1], s);
    s = MFMA(kf2, qf[2], s);
    s = MFMA(kf3, qf[3], s);

    float p[16];
#pragma unroll
    for (int e = 0; e < 16; ++e) p[e] = pexp(s[e]);
    {
      float d0 = (p[0] + p[1]) + (p[2] + p[3]);
      float d1 = (p[4] + p[5]) + (p[6] + p[7]);
      float d2 = (p[8] + p[9]) + (p[10] + p[11]);
      float d3 = (p[12] + p[13]) + (p[14] + p[15]);
      den += (d0 + d1) + (d2 + d3);
    }

    // S regs ARE the O-MFMA A-operand (V k-slots pre-permuted at production)
    uint4_t w0, w1;
#pragma unroll
    for (int j = 0; j < 4; ++j) {
      w0[j] = pkcv(p[2 * j], p[2 * j + 1]);
      w1[j] = pkcv(p[8 + 2 * j], p[9 + 2 * j]);
    }
    short8 pf0 = __builtin_bit_cast(short8, w0);   // m 0..15 of chunk
    short8 pf1 = __builtin_bit_cast(short8, w1);   // m 16..31

    short8 vf0 = ld8(vl + lane * 8);               // ct0 ks0
    short8 vf1 = ld8(vl + 512 + lane * 8);         // ct0 ks1
    short8 vf2 = ld8(vl + 1024 + lane * 8);        // ct1 ks0
    short8 vf3 = ld8(vl + 1536 + lane * 8);        // ct1 ks1

    oc0 = MFMA(pf0, vf0, oc0);
    oc0 = MFMA(pf1, vf1, oc0);
    oc1 = MFMA(pf0, vf2, oc1);
    oc1 = MFMA(pf1, vf3, oc1);

    __syncthreads();   // drains next-tile DMA + frees cur buffer
  }

  den += __shfl_xor(den, 32);   // combine lane halves (m coverage)

  // combine m-chunk partials: O[n][c] (+ den) via LDS atomics
#pragma unroll
  for (int ct = 0; ct < 2; ++ct) {
    const float16_t& oa = ct ? oc1 : oc0;
    const int cc = ct * 32 + l31;
#pragma unroll
    for (int e = 0; e < 16; ++e) {
      const int nr = nsub * 32 + (e & 3) + 8 * (e >> 2) + 4 * lh;
      atomicAdd(&Oacc[nr * OS + cc], oa[e]);
    }
  }
  if (lane < 32) atomicAdd(&Oacc[64 * OS + nsub * 32 + l31], den);
  __syncthreads();

  // normalize + cast -> Ol[n][c] bf16 (8 thr/row)
  {
    const int nloc = t >> 3, c8 = (t & 7) * 8;
    float4_t s0 = *(float4_t*)&Oacc[nloc * OS + c8];
    float4_t s1 = *(float4_t*)&Oacc[nloc * OS + c8 + 4];
    const float r = 1.0f / Oacc[64 * OS + nloc];
    uint4_t o4;
    o4[0] = pkcv(s0[0] * r, s0[1] * r);
    o4[1] = pkcv(s0[2] * r, s0[3] * r);
    o4[2] = pkcv(s1[0] * r, s1[1] * r);
    o4[3] = pkcv(s1[2] * r, s1[3] * r);
    *(uint4_t*)&Ol[nloc * OLS + c8] = o4;
  }
  __syncthreads();

  // fused proj: wave wv -> o-tile wv (32 o), both n-subtiles; raw fp32 W
  float16_t f0 = z16(), f1 = z16();
  const float* pwrow = pw + (wv * 32 + l31) * 64 + lh * 8;
#pragma unroll
  for (int kk = 0; kk < 4; ++kk) {
    float4_t wa = *(const float4_t*)(pwrow + kk * 16);
    float4_t wb = *(const float4_t*)(pwrow + kk * 16 + 4);
    short8 af = pack8f(wa, wb);
    short8 b0 = ld8(&Ol[l31 * OLS + kk * 16 + lh * 8]);
    short8 b1 = ld8(&Ol[(32 + l31) * OLS + kk * 16 + lh * 8]);
    f0 = MFMA(af, b0, f0);
    f1 = MFMA(af, b1, f1);
  }
  const int n0 = nt * 64;
#pragma unroll
  for (int e = 0; e < 16; ++e) {
    const int o = wv * 32 + (e & 3) + 8 * (e >> 2) + 4 * lh;
    const float bv = pb[o];
    out[((b * 256 + o) << 12) + n0 + l31]      = f0[e] + bv;
    out[((b * 256 + o) << 12) + n0 + 32 + l31] = f1[e] + bv;
  }
}

extern "C" void kernel_launch(void* const* d_in, const int* in_sizes, int n_in,
                              void* d_out, int out_size, void* d_ws, size_t ws_size,
                              hipStream_t stream) {
  const float* x      = (const float*)d_in[0];
  const float* qkv_w  = (const float*)d_in[1];
  const float* qkv_b  = (const float*)d_in[2];
  const float* proj_w = (const float*)d_in[3];
  const float* proj_b = (const float*)d_in[4];
  float* out = (float*)d_out;

  unsigned short* ws  = (unsigned short*)d_ws;
  unsigned short* qf  = ws + QOFF;
  unsigned short* kf  = ws + KOFF;
  unsigned short* vf  = ws + VOFF;
  unsigned short* wqs = ws + WQOFF;
  float*          bs  = (float*)(ws + BSOFF);

  k_prep<<<24, 256, 0, stream>>>(qkv_w, qkv_b, wqs, bs);
  k_qkv<<<512, 384, 0, stream>>>(x, wqs, bs, qf, kf, vf);
  k_attn<<<256, 512, 0, stream>>>(qf, kf, vf, proj_w, proj_b, out);
}

// Round 9
// 132.151 us; speedup vs baseline: 1.0847x; 1.0847x over previous
//
#include <hip/hip_runtime.h>
#include <hip/hip_bf16.h>

// EfficientAttention: x(4,256,64,64) -> qkv(192ch) -> attn(N=4096,c=64) -> proj(256ch)
// k_prep: qkv weights fp32->bf16 frag layout (QSC folded into Q rows/bias).
// k_qkv : 256 blocks x 64-token tiles, 6 waves; per-wave weight frag shared
//         across both 32-n subtiles. Frag-swizzled outputs:
//   Qf/Kf: [b][chunk32][kk(4)][lane(64)][8]
//   Vf   : [b][chunk32][ct(2)ks(2)][lane(64)][j(8)] = producer reg order
// k_attn: 256-token K/V tiles (128KB LDS dbuf via global_load_lds), 16
//         barriers total (was 32) with a full tile of compute covering each
//         DMA drain — discriminating test: barrier-drain vs per-inst stall.

#define N_TOK 4096
#define CDIM  64
#define DIM   256
#define NBAT  4

typedef __attribute__((ext_vector_type(8)))  short          short8;
typedef __attribute__((ext_vector_type(8)))  unsigned short ushort8_t;
typedef __attribute__((ext_vector_type(4)))  unsigned short ushort4_t;
typedef __attribute__((ext_vector_type(4)))  unsigned int   uint4_t;
typedef __attribute__((ext_vector_type(4)))  float          float4_t;
typedef __attribute__((ext_vector_type(16))) float          float16_t;

#if __has_builtin(__builtin_amdgcn_exp2f)
#define QSC  0.18033688011112042f   /* 0.125 * log2(e): p = exp2(s) */
#define PEXP(x) __builtin_amdgcn_exp2f(x)
#else
#define QSC  0.125f
#define PEXP(x) __expf(x)
#endif

__device__ __forceinline__ unsigned short f2bf(float f) {
  unsigned int u = __builtin_bit_cast(unsigned int, f);
  u += 0x7fffu + ((u >> 16) & 1u);            // RNE
  return (unsigned short)(u >> 16);
}

// packed f32x2 -> bf16x2 dword (v_cvt_pk_bf16_f32 on gfx950, RNE)
__device__ __forceinline__ unsigned int pkcv(float a, float b) {
  __hip_bfloat162 h = __float22bfloat162_rn(make_float2(a, b));
  unsigned int r; __builtin_memcpy(&r, &h, 4); return r;
}

__device__ __forceinline__ short8 ld8(const unsigned short* p) {
  return __builtin_bit_cast(short8, *(const ushort8_t*)p);
}

__device__ __forceinline__ short8 pack8f(float4_t a, float4_t b) {
  uint4_t u;
  u[0] = pkcv(a[0], a[1]); u[1] = pkcv(a[2], a[3]);
  u[2] = pkcv(b[0], b[1]); u[3] = pkcv(b[2], b[3]);
  return __builtin_bit_cast(short8, u);
}

__device__ __forceinline__ float16_t z16() {
  float16_t r;
#pragma unroll
  for (int i = 0; i < 16; ++i) r[i] = 0.0f;
  return r;
}

// async global->LDS DMA: 64 lanes x 16B; LDS dst = wave-uniform base (+lane*16 by HW)
typedef __attribute__((address_space(1))) const void* gvp;
typedef __attribute__((address_space(3))) void*       lvp;
__device__ __forceinline__ void dma16(const unsigned short* g, unsigned short* l) {
  __builtin_amdgcn_global_load_lds((gvp)g, (lvp)l, 16, 0, 0);
}

#define MFMA(a, b, c) __builtin_amdgcn_mfma_f32_32x32x16_bf16((a), (b), (c), 0, 0, 0)

// ws layout (u16 units)
#define QOFF  0                // 4*128*4*512 = 1048576 each
#define KOFF  1048576
#define VOFF  2097152
#define WQOFF 3145728          // 192*256
#define BSOFF 3194880          // scaled qkv bias, fp32 (192)

// ---------------------------------------------------------------------------
// k_prep: grid 24 x 256. qkv_w -> bf16 frag layout (Q rows scaled by QSC);
// bias -> fp32 with Q-scale fold.
// ---------------------------------------------------------------------------
__global__ void k_prep(const float* __restrict__ qw, const float* __restrict__ qb,
                       unsigned short* __restrict__ wqs, float* __restrict__ bs)
{
  const int g = blockIdx.x * 256 + threadIdx.x;   // 0..6143
  {
    const int lane = g & 63, grp = g >> 6;
    const int w6 = grp >> 4, kk = grp & 15;
    const int o = w6 * 32 + (lane & 31);
    const int c = kk * 16 + (lane >> 5) * 8;
    const float sc = (o < 64) ? QSC : 1.0f;
    const float* src = qw + o * 256 + c;
    ushort8_t u;
#pragma unroll
    for (int j = 0; j < 8; ++j) u[j] = f2bf(src[j] * sc);
    *(ushort8_t*)(wqs + g * 8) = u;
  }
  if (g < 48) {
    float4_t f = *(const float4_t*)(qb + g * 4);
    float4_t o;
#pragma unroll
    for (int j = 0; j < 4; ++j) o[j] = f[j] * ((g * 4 + j) < 64 ? QSC : 1.0f);
    *(float4_t*)(bs + g * 4) = o;
  }
}

// ---------------------------------------------------------------------------
// k_qkv: grid 256 x 384 thr (6 waves). Block: 64-token tile, all 192 o.
// Wave w: o-tile w, BOTH 32-n subtiles (weight frag shared).
// Waves 0-3 (Q,K): C[o rows][n cols]; waves 4-5 (V): swapped operands.
// ---------------------------------------------------------------------------
#define RS 132   // Xl row stride in dwords

__global__ __launch_bounds__(384, 2) void k_qkv(
    const float* __restrict__ x, const unsigned short* __restrict__ wqs,
    const float* __restrict__ bs, unsigned short* __restrict__ Qf,
    unsigned short* __restrict__ Kf, unsigned short* __restrict__ Vf)
{
  __shared__ unsigned int Xl[64 * RS];
  const int id = blockIdx.x;
  const int b  = (id >> 1) & 3;
  const int nt = (id & 1) | ((id >> 3) << 1);   // 0..63 (64-token tile)
  const int t  = threadIdx.x;
  const int n0g = nt * 64;

  if (t < 256) {
    const int n0  = (t & 15) * 4;
    const int cpb = t >> 4;                      // 0..15
#pragma unroll
    for (int p = 0; p < 8; ++p) {
      const int cp = cpb + 16 * p, c = cp * 2;
      const float* xb = x + (((size_t)(b * DIM + c)) << 12) + n0g + n0;
      float4_t a = *(const float4_t*)xb;
      float4_t d = *(const float4_t*)(xb + 4096);
#pragma unroll
      for (int j = 0; j < 4; ++j)
        Xl[(n0 + j) * RS + cp] = pkcv(a[j], d[j]);
    }
  }
  __syncthreads();

  const int w = t >> 6, lane = t & 63, l31 = lane & 31, lh = lane >> 5;
  const unsigned short* wrow = wqs + ((w * 16) << 9) + lane * 8;
  const unsigned int*   xr0  = &Xl[l31 * RS + lh * 4];
  const unsigned int*   xr1  = &Xl[(32 + l31) * RS + lh * 4];

  float16_t a0 = z16(), a1 = z16();
  if (w < 4) {
#pragma unroll
    for (int kk = 0; kk < 16; ++kk) {
      short8 wf = ld8(wrow + (kk << 9));
      short8 x0 = __builtin_bit_cast(short8, *(const uint4_t*)(xr0 + kk * 8));
      short8 x1 = __builtin_bit_cast(short8, *(const uint4_t*)(xr1 + kk * 8));
      a0 = MFMA(wf, x0, a0);                     // C[o rows][n cols], sub 0
      a1 = MFMA(wf, x1, a1);                     // sub 1
    }
  } else {
#pragma unroll
    for (int kk = 0; kk < 16; ++kk) {
      short8 wf = ld8(wrow + (kk << 9));
      short8 x0 = __builtin_bit_cast(short8, *(const uint4_t*)(xr0 + kk * 8));
      short8 x1 = __builtin_bit_cast(short8, *(const uint4_t*)(xr1 + kk * 8));
      a0 = MFMA(x0, wf, a0);                     // C[token rows][c cols]
      a1 = MFMA(x1, wf, a1);
    }
  }

  if (w < 4) {
    unsigned short* dst = (w < 2) ? Qf : Kf;
    const int w2 = w & 1;                        // c64-half of Q or K
#pragma unroll
    for (int sub = 0; sub < 2; ++sub) {
      const float16_t& aa = sub ? a1 : a0;
      const int ch = nt * 2 + sub;               // global 32-token chunk
#pragma unroll
      for (int p = 0; p < 4; ++p) {
        const int o = w * 32 + p * 8 + lh * 4;   // global qkv channel
        float4_t bv = *(const float4_t*)(bs + o);
        ushort4_t pk4;
#pragma unroll
        for (int q = 0; q < 4; ++q) pk4[q] = f2bf(aa[p * 4 + q] + bv[q]);
        const int kkt = w2 * 2 + (p >> 1);
        *(ushort4_t*)(dst + ((((b * 128 + ch) * 4 + kkt) << 9)
                             + (l31 + 32 * (p & 1)) * 8 + lh * 4)) = pk4;
      }
    }
  } else {
    const int ct = w - 4;                        // c-group of V
    const float bvs = bs[128 + ct * 32 + l31];
#pragma unroll
    for (int sub = 0; sub < 2; ++sub) {
      const float16_t& aa = sub ? a1 : a0;
      const int ch = nt * 2 + sub;
#pragma unroll
      for (int ks = 0; ks < 2; ++ks) {
        ushort8_t pk8;
#pragma unroll
        for (int j = 0; j < 8; ++j) pk8[j] = f2bf(aa[ks * 8 + j] + bvs);
        *(ushort8_t*)(Vf + ((((b * 128 + ch) * 4 + ct * 2 + ks) << 9)
                            + lane * 8)) = pk8;
      }
    }
  }
}

// ---------------------------------------------------------------------------
// k_attn: grid 256 x 512 thr (8 waves). Block: 64 q-rows.
// Outer: 16 tiles of 256 tokens (8 chunks), LDS dbuf via global_load_lds.
// Staging: waves 0-3 K chunks {2w,2w+1}; waves 4-7 V likewise (8KB/wave/tile).
// Compute: wave wv -> m-chunks {2mq, 2mq+1} of the tile, n-subtile (wv&1).
// One barrier per tile (16 total) — DMA drain covered by a full tile.
// ---------------------------------------------------------------------------
#define OS   68    // Oacc row stride (fp32)
#define OLS  72    // Ol row stride (bf16)
#define NACC (64 * OS + 64)

__global__ __launch_bounds__(512, 1) void k_attn(
    const unsigned short* __restrict__ Qf, const unsigned short* __restrict__ Kf,
    const unsigned short* __restrict__ Vf, const float* __restrict__ pw,
    const float* __restrict__ pb, float* __restrict__ out)
{
  __shared__ __align__(16) unsigned short KV[2][2][16384]; // [buf][K|V][8ch*2048]
  __shared__ float Oacc[NACC];                             // O[n][c] + den tail
  __shared__ __align__(16) unsigned short Ol[64 * OLS];

  const int id = blockIdx.x;
  const int b  = (id >> 1) & 3;
  const int nt = (id & 1) | ((id >> 3) << 1);        // 0..63
  const int t  = threadIdx.x;
  const int wv = t >> 6, lane = t & 63, l31 = lane & 31, lh = lane >> 5;
  const int mq = wv >> 1, nsub = wv & 1;

  for (int i = t; i < NACC; i += 512) Oacc[i] = 0.0f;

  // staging role: wave stages 2 chunks of K (wv<4) or V (wv>=4)
  const int kvsel = wv >> 2;
  const int wq2   = (wv & 3) * 2;                    // first staged chunk in tile
  const unsigned short* sg = ((kvsel == 0) ? Kf : Vf)
                             + (((size_t)(b * 128 + wq2)) << 11) + lane * 8;

  // Q frags (QSC pre-folded)
  short8 qf[4];
#pragma unroll
  for (int kk = 0; kk < 4; ++kk)
    qf[kk] = ld8(Qf + (((b * 128 + nt * 2 + nsub) * 4 + kk) << 9) + lane * 8);

  // stage tile 0 into buf 0
#pragma unroll
  for (int c2 = 0; c2 < 2; ++c2)
#pragma unroll
    for (int kk = 0; kk < 4; ++kk)
      dma16(sg + (c2 << 11) + (kk << 9),
            &KV[0][kvsel][((wq2 + c2) << 11) + (kk << 9)]);

  float16_t oc0 = z16(), oc1 = z16();
  float den = 0.0f;

  __syncthreads();   // Oacc zeroed + tile 0 resident

  for (int t4 = 0; t4 < 16; ++t4) {
    const int cur = t4 & 1;

    // stage tile t4+1 (drained at the NEXT barrier, a full tile later)
    if (t4 < 15) {
      const unsigned short* g = sg + (((size_t)(t4 + 1)) << 14);
#pragma unroll
      for (int c2 = 0; c2 < 2; ++c2)
#pragma unroll
        for (int kk = 0; kk < 4; ++kk)
          dma16(g + (c2 << 11) + (kk << 9),
                &KV[cur ^ 1][kvsel][((wq2 + c2) << 11) + (kk << 9)]);
    }

#pragma unroll
    for (int cc = 0; cc < 2; ++cc) {
      const int ch = mq * 2 + cc;                    // my m-chunk in tile
      const unsigned short* kl = &KV[cur][0][ch << 11];
      const unsigned short* vl = &KV[cur][1][ch << 11];

      short8 kf0 = ld8(kl + lane * 8);
      short8 kf1 = ld8(kl + 512 + lane * 8);
      short8 kf2 = ld8(kl + 1024 + lane * 8);
      short8 kf3 = ld8(kl + 1536 + lane * 8);

      // S^T tile: lane col n = l31, row m = (e&3)+8*(e>>2)+4*lh
      float16_t s = z16();
      s = MFMA(kf0, qf[0], s);
      s = MFMA(kf1, qf[1], s);
      s = MFMA(kf2, qf[2], s);
      s = MFMA(kf3, qf[3], s);

      float p[16];
#pragma unroll
      for (int e = 0; e < 16; ++e) p[e] = PEXP(s[e]);
      {
        float d0 = (p[0] + p[1]) + (p[2] + p[3]);
        float d1 = (p[4] + p[5]) + (p[6] + p[7]);
        float d2 = (p[8] + p[9]) + (p[10] + p[11]);
        float d3 = (p[12] + p[13]) + (p[14] + p[15]);
        den += (d0 + d1) + (d2 + d3);
      }

      // S regs ARE the O-MFMA A-operand (V k-slots pre-permuted at production)
      uint4_t w0, w1;
#pragma unroll
      for (int j = 0; j < 4; ++j) {
        w0[j] = pkcv(p[2 * j], p[2 * j + 1]);
        w1[j] = pkcv(p[8 + 2 * j], p[9 + 2 * j]);
      }
      short8 pf0 = __builtin_bit_cast(short8, w0);   // m 0..15 of chunk
      short8 pf1 = __builtin_bit_cast(short8, w1);   // m 16..31

      short8 vf0 = ld8(vl + lane * 8);               // ct0 ks0
      short8 vf1 = ld8(vl + 512 + lane * 8);         // ct0 ks1
      short8 vf2 = ld8(vl + 1024 + lane * 8);        // ct1 ks0
      short8 vf3 = ld8(vl + 1536 + lane * 8);        // ct1 ks1

      oc0 = MFMA(pf0, vf0, oc0);
      oc0 = MFMA(pf1, vf1, oc0);
      oc1 = MFMA(pf0, vf2, oc1);
      oc1 = MFMA(pf1, vf3, oc1);
    }

    __syncthreads();   // drains next-tile DMA + frees cur buffer
  }

  den += __shfl_xor(den, 32);   // combine lane halves (m coverage)

  // combine m-chunk partials: O[n][c] (+ den) via LDS atomics
#pragma unroll
  for (int ct = 0; ct < 2; ++ct) {
    const float16_t& oa = ct ? oc1 : oc0;
    const int cc = ct * 32 + l31;
#pragma unroll
    for (int e = 0; e < 16; ++e) {
      const int nr = nsub * 32 + (e & 3) + 8 * (e >> 2) + 4 * lh;
      atomicAdd(&Oacc[nr * OS + cc], oa[e]);
    }
  }
  if (lane < 32) atomicAdd(&Oacc[64 * OS + nsub * 32 + l31], den);
  __syncthreads();

  // normalize + cast -> Ol[n][c] bf16 (8 thr/row)
  {
    const int nloc = t >> 3, c8 = (t & 7) * 8;
    float4_t s0 = *(float4_t*)&Oacc[nloc * OS + c8];
    float4_t s1 = *(float4_t*)&Oacc[nloc * OS + c8 + 4];
    const float r = 1.0f / Oacc[64 * OS + nloc];
    uint4_t o4;
    o4[0] = pkcv(s0[0] * r, s0[1] * r);
    o4[1] = pkcv(s0[2] * r, s0[3] * r);
    o4[2] = pkcv(s1[0] * r, s1[1] * r);
    o4[3] = pkcv(s1[2] * r, s1[3] * r);
    *(uint4_t*)&Ol[nloc * OLS + c8] = o4;
  }
  __syncthreads();

  // fused proj: wave wv -> o-tile wv (32 o), both n-subtiles; raw fp32 W
  float16_t f0 = z16(), f1 = z16();
  const float* pwrow = pw + (wv * 32 + l31) * 64 + lh * 8;
#pragma unroll
  for (int kk = 0; kk < 4; ++kk) {
    float4_t wa = *(const float4_t*)(pwrow + kk * 16);
    float4_t wb = *(const float4_t*)(pwrow + kk * 16 + 4);
    short8 af = pack8f(wa, wb);
    short8 b0 = ld8(&Ol[l31 * OLS + kk * 16 + lh * 8]);
    short8 b1 = ld8(&Ol[(32 + l31) * OLS + kk * 16 + lh * 8]);
    f0 = MFMA(af, b0, f0);
    f1 = MFMA(af, b1, f1);
  }
  const int n0 = nt * 64;
#pragma unroll
  for (int e = 0; e < 16; ++e) {
    const int o = wv * 32 + (e & 3) + 8 * (e >> 2) + 4 * lh;
    const float bv = pb[o];
    out[((b * 256 + o) << 12) + n0 + l31]      = f0[e] + bv;
    out[((b * 256 + o) << 12) + n0 + 32 + l31] = f1[e] + bv;
  }
}

extern "C" void kernel_launch(void* const* d_in, const int* in_sizes, int n_in,
                              void* d_out, int out_size, void* d_ws, size_t ws_size,
                              hipStream_t stream) {
  const float* x      = (const float*)d_in[0];
  const float* qkv_w  = (const float*)d_in[1];
  const float* qkv_b  = (const float*)d_in[2];
  const float* proj_w = (const float*)d_in[3];
  const float* proj_b = (const float*)d_in[4];
  float* out = (float*)d_out;

  unsigned short* ws  = (unsigned short*)d_ws;
  unsigned short* qf  = ws + QOFF;
  unsigned short* kf  = ws + KOFF;
  unsigned short* vf  = ws + VOFF;
  unsigned short* wqs = ws + WQOFF;
  float*          bs  = (float*)(ws + BSOFF);

  k_prep<<<24, 256, 0, stream>>>(qkv_w, qkv_b, wqs, bs);
  k_qkv<<<256, 384, 0, stream>>>(x, wqs, bs, qf, kf, vf);
  k_attn<<<256, 512, 0, stream>>>(qf, kf, vf, proj_w, proj_b, out);
}